// Round 11
// baseline (287.398 us; speedup 1.0000x reference)
//
#include <hip/hip_runtime.h>

// Problem constants
#define NH 16
#define HD 64
#define CE 1024
#define TT 2048
#define BB 4
#define MM 8192   // B*T

using bf16x8 = __attribute__((ext_vector_type(8))) __bf16;
using f32x4  = __attribute__((ext_vector_type(4))) float;
using f32x16 = __attribute__((ext_vector_type(16))) float;

__device__ __forceinline__ unsigned short f2bf(float f) {
  unsigned int u = __float_as_uint(f);
  u += 0x7fffu + ((u >> 16) & 1u);   // RNE
  return (unsigned short)(u >> 16);
}

// pack two f32 -> one u32 of 2 bf16 (no builtin on gfx950; m240)
__device__ __forceinline__ unsigned cvtpk(float lo, float hi) {
  unsigned r;
  asm("v_cvt_pk_bf16_f32 %0, %1, %2" : "=v"(r) : "v"(lo), "v"(hi));
  return r;
}

// async global->LDS, 16B per lane; LDS dst must be wave-uniform (HW adds lane*16)
__device__ __forceinline__ void async_cp16(const unsigned short* g, unsigned short* l) {
  __builtin_amdgcn_global_load_lds(
      (const __attribute__((address_space(1))) unsigned int*)g,
      (__attribute__((address_space(3))) unsigned int*)l, 16, 0, 0);
}

// ---------------- fused prep: convert_x + transpose(w_qkv) + transpose(w_out) ------------------
__global__ __launch_bounds__(256) void prep(const float* __restrict__ x,
                                            const float* __restrict__ w_qkv,
                                            const float* __restrict__ w_out,
                                            unsigned short* __restrict__ Xb,
                                            unsigned short* __restrict__ Wt1,
                                            unsigned short* __restrict__ Wt2) {
  __shared__ unsigned short tile[32][33];
  const int idx = blockIdx.x;
  if (idx < 8192) {
    const int i = (idx * 256 + threadIdx.x) * 4;
    const float4 v = *(const float4*)(x + i);
    ushort4 o;
    o.x = f2bf(v.x); o.y = f2bf(v.y); o.z = f2bf(v.z); o.w = f2bf(v.w);
    *(ushort4*)(Xb + i) = o;
    return;
  }
  const float* in;
  unsigned short* out;
  int rows, cols, bx, by;
  if (idx < 11264) {
    const int tc = idx - 8192;
    in = w_qkv; out = Wt1; rows = 1024; cols = 3072;
    bx = tc % 96; by = tc / 96;
  } else {
    const int tc = idx - 11264;
    in = w_out; out = Wt2; rows = 1024; cols = 1024;
    bx = tc & 31; by = tc >> 5;
  }
  const int c0 = bx * 32, r0 = by * 32;
  const int tx = threadIdx.x & 31, ty = threadIdx.x >> 5;  // ty 0..7
#pragma unroll
  for (int i = ty; i < 32; i += 8)
    tile[i][tx] = f2bf(in[(size_t)(r0 + i) * cols + c0 + tx]);
  __syncthreads();
#pragma unroll
  for (int i = ty; i < 32; i += 8)
    out[(size_t)(c0 + i) * rows + r0 + tx] = tile[tx][i];
}

// ---------------- GEMM core: T3 minimum-2-phase (double-buffered LDS, single barrier) ----------
__device__ __forceinline__ void gemm_core(const unsigned short* __restrict__ A,
                                          const unsigned short* __restrict__ BT,
                                          int m0, int n0, f32x4 (&acc)[4][4],
                                          unsigned short* As, unsigned short* Bs) {
  const int tid  = threadIdx.x;
  const int lane = tid & 63;
  const int wave = tid >> 6;
  const int quad = lane >> 4;
  const int l15  = lane & 15;
  const int wm = (wave & 1) * 64;
  const int wn = (wave >> 1) * 64;
  const int ldr = tid >> 2;         // 0..63
  const int ldc = (tid & 3) * 8;    // 0,8,16,24
  const unsigned short* Ap = A + (size_t)(m0 + ldr) * CE + ldc;
  const unsigned short* Bp = BT + (size_t)(n0 + ldr) * CE + ldc;
  const int wofs = wave * 512;
#define STAGE_K(buf, k0)                                                   \
  do {                                                                     \
    async_cp16(Ap + (k0), As + (buf) * 4096 + wofs);                       \
    async_cp16(Ap + (size_t)64 * CE + (k0), As + (buf) * 4096 + 2048 + wofs); \
    async_cp16(Bp + (k0), Bs + (buf) * 4096 + wofs);                       \
    async_cp16(Bp + (size_t)64 * CE + (k0), Bs + (buf) * 4096 + 2048 + wofs); \
  } while (0)
  STAGE_K(0, 0);
  __syncthreads();
  int cur = 0;
  for (int k0 = 0; k0 < CE; k0 += 32) {
    if (k0 + 32 < CE) STAGE_K(cur ^ 1, k0 + 32);   // issue next tile first; flies during MFMAs
    const unsigned short* Ab = As + cur * 4096;
    const unsigned short* Bb = Bs + cur * 4096;
    bf16x8 af[4], bfr[4];
#pragma unroll
    for (int i = 0; i < 4; i++) {
      af[i]  = *(const bf16x8*)&Ab[(wm + i * 16 + l15) * 32 + quad * 8];
      bfr[i] = *(const bf16x8*)&Bb[(wn + i * 16 + l15) * 32 + quad * 8];
    }
    __builtin_amdgcn_s_setprio(1);
#pragma unroll
    for (int mi = 0; mi < 4; mi++)
#pragma unroll
      for (int ni = 0; ni < 4; ni++)
        acc[mi][ni] = __builtin_amdgcn_mfma_f32_16x16x32_bf16(af[mi], bfr[ni], acc[mi][ni], 0, 0, 0);
    __builtin_amdgcn_s_setprio(0);
    __syncthreads();   // single barrier per K-step (drains vmcnt after the MFMAs, not before)
    cur ^= 1;
  }
#undef STAGE_K
}

// ---------------- GEMM 1: qkv = x @ w_qkv -> Q (scaled), K, and V written TRANSPOSED -----------
__global__ __launch_bounds__(256) void gemm_qkv(const unsigned short* __restrict__ A,
                                                const unsigned short* __restrict__ BT,
                                                unsigned short* __restrict__ Qb,
                                                unsigned short* __restrict__ Kb,
                                                unsigned short* __restrict__ Vtb) {
  __shared__ unsigned short pool[16384];  // As dbuf | Bs dbuf; V-epilogue aliases
  f32x4 acc[4][4] = {};
  const int m0 = blockIdx.y * 128, n0 = blockIdx.x * 128;
  gemm_core(A, BT, m0, n0, acc, pool, pool + 8192);
  const int tid = threadIdx.x, lane = tid & 63, wave = tid >> 6;
  const int quad = lane >> 4, l15 = lane & 15;
  const int wm = (wave & 1) * 64, wn = (wave >> 1) * 64;
  if (blockIdx.x >= 16) {
    // ---- V: transpose tile through LDS, write Vtb[bh][d][t] coalesced ----
    unsigned short* Vt = pool;                 // [128 d][66], aliases (safe after last barrier)
    const int h0 = 2 * (blockIdx.x - 16);      // first head of this 128-col tile
    const int bb = m0 >> 11;                   // batch (tile never crosses: 2048%128==0)
    const int t0g = m0 & 2047;
    const int l31 = tid & 31;
    const int rw  = tid >> 5;                  // 0..7
    unsigned int* __restrict__ VtU = (unsigned int*)Vtb;
#pragma unroll
    for (int hp = 0; hp < 2; hp++) {           // two passes of 64 t-rows
      __syncthreads();                         // prior pass reads (or gemm reads) done
      if ((wave & 1) == hp) {                  // waves whose wm == 64*hp own these t rows
#pragma unroll
        for (int mi = 0; mi < 4; mi++)
#pragma unroll
          for (int ni = 0; ni < 4; ni++) {
            const int row = wn + ni * 16 + l15;      // d-local 0..127
            const int col = mi * 16 + quad * 4;      // t-local 0..63 (+r)
#pragma unroll
            for (int r = 0; r < 4; r++)
              Vt[row * 66 + col + r] = f2bf(acc[mi][ni][r]);
          }
      }
      __syncthreads();
      // write out: 128 d-rows x 32 u32 (64 t), 8 rows in parallel
#pragma unroll
      for (int k = 0; k < 16; k++) {
        const int d = rw + 8 * k;              // 0..127
        const unsigned int v = *(const unsigned int*)&Vt[d * 66 + 2 * l31];
        const int hh = h0 + (d >> 6);
        VtU[((((size_t)(bb * 16 + hh) * 64 + (d & 63)) * TT + t0g + 64 * hp) >> 1) + l31] = v;
      }
    }
    return;
  }
  // ---- Q / K: direct scatter (coalesced over l15 -> d) ----
  const float QSCALE = 0.125f * 1.44269504088896340736f;
#pragma unroll
  for (int mi = 0; mi < 4; mi++) {
#pragma unroll
    for (int ni = 0; ni < 4; ni++) {
      const int n = n0 + wn + ni * 16 + l15;
      const int s = n >> 10;           // 0=q 1=k
      const int h = (n >> 6) & 15;
      const int d = n & 63;
#pragma unroll
      for (int r = 0; r < 4; r++) {
        const int m = m0 + wm + mi * 16 + quad * 4 + r;
        const int b = m >> 11;         // /2048
        const int t = m & 2047;
        const int bh = (b << 4) + h;
        const float v = acc[mi][ni][r];
        if (s == 0) Qb[((size_t)bh * TT + t) * HD + d] = f2bf(v * QSCALE);
        else        Kb[((size_t)bh * TT + t) * HD + d] = f2bf(v);
      }
    }
  }
}

// ---------------- GEMM 2: out = AO @ w_out + b_out (fp32 out) ----------------
__global__ __launch_bounds__(256) void gemm_out(const unsigned short* __restrict__ A,
                                                const unsigned short* __restrict__ BT,
                                                const float* __restrict__ bias,
                                                float* __restrict__ out) {
  __shared__ unsigned short pool[16384];
  f32x4 acc[4][4] = {};
  const int m0 = blockIdx.y * 128, n0 = blockIdx.x * 128;
  gemm_core(A, BT, m0, n0, acc, pool, pool + 8192);
  const int tid = threadIdx.x, lane = tid & 63, wave = tid >> 6;
  const int quad = lane >> 4, l15 = lane & 15;
  const int wm = (wave & 1) * 64, wn = (wave >> 1) * 64;
#pragma unroll
  for (int mi = 0; mi < 4; mi++) {
#pragma unroll
    for (int ni = 0; ni < 4; ni++) {
      const int n = n0 + wn + ni * 16 + l15;
      const float bv = bias[n];
#pragma unroll
      for (int r = 0; r < 4; r++) {
        const int m = m0 + wm + mi * 16 + quad * 4 + r;
        out[(size_t)m * CE + n] = acc[mi][ni][r] + bv;
      }
    }
  }
}

// ---------------- causal flash attention: 32x32 MFMA, swapped QK^T, in-register P (T12) --------
// Macro-structure = R4-verbatim (the 4x-validated local optimum): 128-row Q tiles, grid (8,64),
// qx/(15-qx) pairing (34 iters/block, perfect balance), KV tile 64 staged once per block,
// one-iteration-ahead register prefetch before the barrier, T1 XCD swizzle, T5 setprio.
// Micro-structure replaced: 256 thr / 4 waves, wave owns 32 q-rows via 32x32x16 MFMAs.
// Swapped QK^T (A=K, B=Q) -> P[q=lane&31][kv=(r&3)+8(r>>2)+4hi] in registers; T12 cvt_pk +
// permlane32_swap builds the PV A-fragment with ZERO LDS ops -- the 18-op/16-row P LDS
// round-trip (the dominant term of the measured ~95% LDS-pipe saturation) is gone entirely.
// Per wave-iter: 18 ds_read_b128, 20 MFMA, no Ps buffer (LDS 36.9 -> 18.4 KB).
__global__ __launch_bounds__(256) void flash_attn(const unsigned short* __restrict__ Q,
                                                  const unsigned short* __restrict__ Kg,
                                                  const unsigned short* __restrict__ Vt,
                                                  unsigned short* __restrict__ AO) {
  __shared__ unsigned short Ks[64][72];     // [kv][d]
  __shared__ unsigned short Vs[64][72];     // [d][kv]
  const int flat = blockIdx.x + 8 * blockIdx.y;        // 0..511, hw dispatch order
  const int wu   = (flat & 7) * 64 + (flat >> 3);      // bijective remap
  const int qx   = wu & 7;                             // q-tile index 0..7
  const int bh   = wu >> 3;                            // head 0..63 (8 consecutive heads/XCD)
  const int tid = threadIdx.x, w = tid >> 6, lane = tid & 63;
  const int l31 = lane & 31, hi = lane >> 5;
  const int b = bh >> 4, h = bh & 15;
  const unsigned short* Kbase = Kg + (size_t)bh * TT * HD;
  const unsigned short* Vbase = Vt + (size_t)bh * HD * TT;
  const int srow = tid >> 2;        // 0..63
  const int scol = (tid & 3) * 16;  // 0,16,32,48
  const bf16x8 ones = {1, 1, 1, 1, 1, 1, 1, 1};

  for (int ph = 0; ph < 2; ph++) {
    const int pt = ph ? (15 - qx) : qx;
    const int q0 = pt * 128;
    const int n_it = 2 * pt + 2;
    const int wr = q0 + w * 32;       // this wave's first Q row (32 rows)
    // Q fragments: B-operand of swapped QK^T. B[n=q=l31][k=ds*16+hi*8+j]
    bf16x8 qf[4];
#pragma unroll
    for (int ds_ = 0; ds_ < 4; ds_++)
      qf[ds_] = *(const bf16x8*)(Q + ((size_t)bh * TT + wr + l31) * HD + ds_ * 16 + hi * 8);
    f32x16 o0 = {}, o1 = {}, l_acc = {};
    // initial prefetch (tile 0 of this phase)
    uint4 kreg[2], vreg[2];
    {
      const unsigned short* kp = Kbase + (size_t)srow * HD + scol;
      kreg[0] = *(const uint4*)kp;
      kreg[1] = *(const uint4*)(kp + 8);
      const unsigned short* vp = Vbase + (size_t)srow * TT + scol;
      vreg[0] = *(const uint4*)vp;
      vreg[1] = *(const uint4*)(vp + 8);
    }
    for (int it = 0; it < n_it; it++) {
      const int kv0 = it * 64;
      // commit prefetched tile to LDS
      *(uint4*)&Ks[srow][scol]     = kreg[0];
      *(uint4*)&Ks[srow][scol + 8] = kreg[1];
      *(uint4*)&Vs[srow][scol]     = vreg[0];
      *(uint4*)&Vs[srow][scol + 8] = vreg[1];
      // issue next tile's loads BEFORE the barrier; they fly across it and during compute
      {
        const int itn = (it + 1 < n_it) ? it + 1 : it;
        const int kvn = itn * 64;
        const unsigned short* kp = Kbase + (size_t)(kvn + srow) * HD + scol;
        kreg[0] = *(const uint4*)kp;
        kreg[1] = *(const uint4*)(kp + 8);
        const unsigned short* vp = Vbase + (size_t)srow * TT + kvn + scol;
        vreg[0] = *(const uint4*)vp;
        vreg[1] = *(const uint4*)(vp + 8);
      }
      __syncthreads();
      // waves fully above this KV tile contribute nothing: skip (wave-uniform)
      if (kv0 <= wr + 31) {
        const int qg = wr + l31;      // this lane's global q row (QK^T output col)
#pragma unroll
        for (int kt = 0; kt < 2; kt++) {
          // S^T = K Q^T over this 32-kv sub-tile: A[m=kv=l31][k], chained over 4 d-slices
          f32x16 sc = {};
          __builtin_amdgcn_s_setprio(1);
#pragma unroll
          for (int ds_ = 0; ds_ < 4; ds_++) {
            const bf16x8 kb = *(const bf16x8*)&Ks[kt * 32 + l31][ds_ * 16 + hi * 8];
            sc = __builtin_amdgcn_mfma_f32_32x32x16_bf16(kb, qf[ds_], sc, 0, 0, 0);
          }
          __builtin_amdgcn_s_setprio(0);
          // P = exp2(S), causal mask; value (reg r): kv = kv0+kt*32+(r&3)+8*(r>>2)+4*hi, q = qg
          float p[16];
          const int kvb = kv0 + kt * 32 + 4 * hi;
          if (kv0 + 63 > wr) {
#pragma unroll
            for (int r = 0; r < 16; r++) {
              const int kvg = kvb + (r & 3) + 8 * (r >> 2);
              p[r] = exp2f(kvg <= qg ? sc[r] : -1e30f);
            }
          } else {
#pragma unroll
            for (int r = 0; r < 16; r++) p[r] = exp2f(sc[r]);
          }
          // T12: cvt_pk + permlane32_swap -> PV A-fragments (16-kv slices), zero LDS ops.
          // slice regs 8s..8s+7; swap(a0,a2)->(w0,w2), swap(a1,a3)->(w1,w3).
          bf16x8 pa[2];
#pragma unroll
          for (int sl = 0; sl < 2; sl++) {
            unsigned a0 = cvtpk(p[8 * sl + 0], p[8 * sl + 1]);
            unsigned a1 = cvtpk(p[8 * sl + 2], p[8 * sl + 3]);
            unsigned a2 = cvtpk(p[8 * sl + 4], p[8 * sl + 5]);
            unsigned a3 = cvtpk(p[8 * sl + 6], p[8 * sl + 7]);
            asm volatile("v_permlane32_swap_b32 %0, %1" : "+v"(a0), "+v"(a2));
            asm volatile("v_permlane32_swap_b32 %0, %1" : "+v"(a1), "+v"(a3));
            union { unsigned u[4]; bf16x8 v; } c;
            c.u[0] = a0; c.u[1] = a1; c.u[2] = a2; c.u[3] = a3;
            pa[sl] = c.v;
          }
          // l += row-sum(P); O += P @ V  (B[n=d=l31(+32)][k=kv slice])
          __builtin_amdgcn_s_setprio(1);
          l_acc = __builtin_amdgcn_mfma_f32_32x32x16_bf16(pa[0], ones, l_acc, 0, 0, 0);
          l_acc = __builtin_amdgcn_mfma_f32_32x32x16_bf16(pa[1], ones, l_acc, 0, 0, 0);
#pragma unroll
          for (int sl = 0; sl < 2; sl++) {
            const bf16x8 vb0 = *(const bf16x8*)&Vs[l31][kt * 32 + sl * 16 + hi * 8];
            const bf16x8 vb1 = *(const bf16x8*)&Vs[32 + l31][kt * 32 + sl * 16 + hi * 8];
            o0 = __builtin_amdgcn_mfma_f32_32x32x16_bf16(pa[sl], vb0, o0, 0, 0, 0);
            o1 = __builtin_amdgcn_mfma_f32_32x32x16_bf16(pa[sl], vb1, o1, 0, 0, 0);
          }
          __builtin_amdgcn_s_setprio(0);
        }
      }
      __syncthreads();  // LDS reads done before next iteration's commit
    }
    // epilogue: O row q = (r&3)+8*(r>>2)+4*hi (same reg-indexing as l_acc), col d = dt*32+l31
    {
      float rin[16];
#pragma unroll
      for (int r = 0; r < 16; r++) rin[r] = __builtin_amdgcn_rcpf(l_acc[r]);
#pragma unroll
      for (int r = 0; r < 16; r++) {
        const int row_g = wr + (r & 3) + 8 * (r >> 2) + 4 * hi;
        const size_t base = ((size_t)b * TT + row_g) * CE + h * 64;
        AO[base + l31]      = f2bf(o0[r] * rin[r]);
        AO[base + 32 + l31] = f2bf(o1[r] * rin[r]);
      }
    }
  }
}

extern "C" void kernel_launch(void* const* d_in, const int* in_sizes, int n_in,
                              void* d_out, int out_size, void* d_ws, size_t ws_size,
                              hipStream_t stream) {
  const float* x     = (const float*)d_in[0];  // [4,2048,1024] f32
  const float* w_qkv = (const float*)d_in[1];  // [1024,3072] f32
  const float* w_out = (const float*)d_in[2];  // [1024,1024] f32
  const float* b_out = (const float*)d_in[3];  // [1024] f32
  float* out = (float*)d_out;                  // [4,2048,1024] f32

  unsigned short* ws  = (unsigned short*)d_ws;
  unsigned short* Xb  = ws;                                  // x bf16 [8192][1024]
  unsigned short* Wt1 = Xb  + (size_t)MM * CE;               // w_qkv^T  [3072][1024]
  unsigned short* Wt2 = Wt1 + (size_t)3072 * 1024;           // w_out^T  [1024][1024]
  unsigned short* Qb  = Wt2 + (size_t)1024 * 1024;           // [BH][T][64]
  unsigned short* Kb  = Qb  + (size_t)8388608;               // [BH][T][64]
  unsigned short* Vtb = Kb  + (size_t)8388608;               // [BH][64][T] (written by gemm_qkv)
  unsigned short* AO  = Vtb + (size_t)8388608;               // [M][1024] bf16

  prep      <<<dim3(12288), 256, 0, stream>>>(x, w_qkv, w_out, Xb, Wt1, Wt2);
  gemm_qkv  <<<dim3(24, 64), 256, 0, stream>>>(Xb, Wt1, Qb, Kb, Vtb);
  flash_attn<<<dim3(8, 64), 256, 0, stream>>>(Qb, Kb, Vtb, AO);
  gemm_out  <<<dim3(8, 64), 256, 0, stream>>>(AO, Wt2, b_out, out);
}

// Round 12
// 257.178 us; speedup vs baseline: 1.1175x; 1.1175x over previous
//
#include <hip/hip_runtime.h>

// Problem constants
#define NH 16
#define HD 64
#define CE 1024
#define TT 2048
#define BB 4
#define MM 8192   // B*T

using bf16x8 = __attribute__((ext_vector_type(8))) __bf16;
using f32x4  = __attribute__((ext_vector_type(4))) float;
using f32x16 = __attribute__((ext_vector_type(16))) float;

__device__ __forceinline__ unsigned short f2bf(float f) {
  unsigned int u = __float_as_uint(f);
  u += 0x7fffu + ((u >> 16) & 1u);   // RNE
  return (unsigned short)(u >> 16);
}

// pack two f32 -> one u32 of 2 bf16 (no builtin on gfx950; m240)
__device__ __forceinline__ unsigned cvtpk(float lo, float hi) {
  unsigned r;
  asm("v_cvt_pk_bf16_f32 %0, %1, %2" : "=v"(r) : "v"(lo), "v"(hi));
  return r;
}

// async global->LDS, 16B per lane; LDS dst must be wave-uniform (HW adds lane*16)
__device__ __forceinline__ void async_cp16(const unsigned short* g, unsigned short* l) {
  __builtin_amdgcn_global_load_lds(
      (const __attribute__((address_space(1))) unsigned int*)g,
      (__attribute__((address_space(3))) unsigned int*)l, 16, 0, 0);
}

// ---------------- fused prep: convert_x + transpose(w_qkv) + transpose(w_out) ------------------
__global__ __launch_bounds__(256) void prep(const float* __restrict__ x,
                                            const float* __restrict__ w_qkv,
                                            const float* __restrict__ w_out,
                                            unsigned short* __restrict__ Xb,
                                            unsigned short* __restrict__ Wt1,
                                            unsigned short* __restrict__ Wt2) {
  __shared__ unsigned short tile[32][33];
  const int idx = blockIdx.x;
  if (idx < 8192) {
    const int i = (idx * 256 + threadIdx.x) * 4;
    const float4 v = *(const float4*)(x + i);
    ushort4 o;
    o.x = f2bf(v.x); o.y = f2bf(v.y); o.z = f2bf(v.z); o.w = f2bf(v.w);
    *(ushort4*)(Xb + i) = o;
    return;
  }
  const float* in;
  unsigned short* out;
  int rows, cols, bx, by;
  if (idx < 11264) {
    const int tc = idx - 8192;
    in = w_qkv; out = Wt1; rows = 1024; cols = 3072;
    bx = tc % 96; by = tc / 96;
  } else {
    const int tc = idx - 11264;
    in = w_out; out = Wt2; rows = 1024; cols = 1024;
    bx = tc & 31; by = tc >> 5;
  }
  const int c0 = bx * 32, r0 = by * 32;
  const int tx = threadIdx.x & 31, ty = threadIdx.x >> 5;  // ty 0..7
#pragma unroll
  for (int i = ty; i < 32; i += 8)
    tile[i][tx] = f2bf(in[(size_t)(r0 + i) * cols + c0 + tx]);
  __syncthreads();
#pragma unroll
  for (int i = ty; i < 32; i += 8)
    out[(size_t)(c0 + i) * rows + r0 + tx] = tile[tx][i];
}

// ---------------- GEMM core: T3 minimum-2-phase (double-buffered LDS, single barrier) ----------
__device__ __forceinline__ void gemm_core(const unsigned short* __restrict__ A,
                                          const unsigned short* __restrict__ BT,
                                          int m0, int n0, f32x4 (&acc)[4][4],
                                          unsigned short* As, unsigned short* Bs) {
  const int tid  = threadIdx.x;
  const int lane = tid & 63;
  const int wave = tid >> 6;
  const int quad = lane >> 4;
  const int l15  = lane & 15;
  const int wm = (wave & 1) * 64;
  const int wn = (wave >> 1) * 64;
  const int ldr = tid >> 2;         // 0..63
  const int ldc = (tid & 3) * 8;    // 0,8,16,24
  const unsigned short* Ap = A + (size_t)(m0 + ldr) * CE + ldc;
  const unsigned short* Bp = BT + (size_t)(n0 + ldr) * CE + ldc;
  const int wofs = wave * 512;
#define STAGE_K(buf, k0)                                                   \
  do {                                                                     \
    async_cp16(Ap + (k0), As + (buf) * 4096 + wofs);                       \
    async_cp16(Ap + (size_t)64 * CE + (k0), As + (buf) * 4096 + 2048 + wofs); \
    async_cp16(Bp + (k0), Bs + (buf) * 4096 + wofs);                       \
    async_cp16(Bp + (size_t)64 * CE + (k0), Bs + (buf) * 4096 + 2048 + wofs); \
  } while (0)
  STAGE_K(0, 0);
  __syncthreads();
  int cur = 0;
  for (int k0 = 0; k0 < CE; k0 += 32) {
    if (k0 + 32 < CE) STAGE_K(cur ^ 1, k0 + 32);   // issue next tile first; flies during MFMAs
    const unsigned short* Ab = As + cur * 4096;
    const unsigned short* Bb = Bs + cur * 4096;
    bf16x8 af[4], bfr[4];
#pragma unroll
    for (int i = 0; i < 4; i++) {
      af[i]  = *(const bf16x8*)&Ab[(wm + i * 16 + l15) * 32 + quad * 8];
      bfr[i] = *(const bf16x8*)&Bb[(wn + i * 16 + l15) * 32 + quad * 8];
    }
    __builtin_amdgcn_s_setprio(1);
#pragma unroll
    for (int mi = 0; mi < 4; mi++)
#pragma unroll
      for (int ni = 0; ni < 4; ni++)
        acc[mi][ni] = __builtin_amdgcn_mfma_f32_16x16x32_bf16(af[mi], bfr[ni], acc[mi][ni], 0, 0, 0);
    __builtin_amdgcn_s_setprio(0);
    __syncthreads();   // single barrier per K-step (drains vmcnt after the MFMAs, not before)
    cur ^= 1;
  }
#undef STAGE_K
}

// ---------------- GEMM 1: qkv = x @ w_qkv -> Q (scaled), K, and V written TRANSPOSED -----------
__global__ __launch_bounds__(256) void gemm_qkv(const unsigned short* __restrict__ A,
                                                const unsigned short* __restrict__ BT,
                                                unsigned short* __restrict__ Qb,
                                                unsigned short* __restrict__ Kb,
                                                unsigned short* __restrict__ Vtb) {
  __shared__ unsigned short pool[16384];  // As dbuf | Bs dbuf; V-epilogue aliases
  f32x4 acc[4][4] = {};
  const int m0 = blockIdx.y * 128, n0 = blockIdx.x * 128;
  gemm_core(A, BT, m0, n0, acc, pool, pool + 8192);
  const int tid = threadIdx.x, lane = tid & 63, wave = tid >> 6;
  const int quad = lane >> 4, l15 = lane & 15;
  const int wm = (wave & 1) * 64, wn = (wave >> 1) * 64;
  if (blockIdx.x >= 16) {
    // ---- V: transpose tile through LDS, write Vtb[bh][d][t] coalesced ----
    unsigned short* Vt = pool;                 // [128 d][66], aliases (safe after last barrier)
    const int h0 = 2 * (blockIdx.x - 16);      // first head of this 128-col tile
    const int bb = m0 >> 11;                   // batch (tile never crosses: 2048%128==0)
    const int t0g = m0 & 2047;
    const int l31 = tid & 31;
    const int rw  = tid >> 5;                  // 0..7
    unsigned int* __restrict__ VtU = (unsigned int*)Vtb;
#pragma unroll
    for (int hp = 0; hp < 2; hp++) {           // two passes of 64 t-rows
      __syncthreads();                         // prior pass reads (or gemm reads) done
      if ((wave & 1) == hp) {                  // waves whose wm == 64*hp own these t rows
#pragma unroll
        for (int mi = 0; mi < 4; mi++)
#pragma unroll
          for (int ni = 0; ni < 4; ni++) {
            const int row = wn + ni * 16 + l15;      // d-local 0..127
            const int col = mi * 16 + quad * 4;      // t-local 0..63 (+r)
#pragma unroll
            for (int r = 0; r < 4; r++)
              Vt[row * 66 + col + r] = f2bf(acc[mi][ni][r]);
          }
      }
      __syncthreads();
      // write out: 128 d-rows x 32 u32 (64 t), 8 rows in parallel
#pragma unroll
      for (int k = 0; k < 16; k++) {
        const int d = rw + 8 * k;              // 0..127
        const unsigned int v = *(const unsigned int*)&Vt[d * 66 + 2 * l31];
        const int hh = h0 + (d >> 6);
        VtU[((((size_t)(bb * 16 + hh) * 64 + (d & 63)) * TT + t0g + 64 * hp) >> 1) + l31] = v;
      }
    }
    return;
  }
  // ---- Q / K: direct scatter (coalesced over l15 -> d) ----
  const float QSCALE = 0.125f * 1.44269504088896340736f;
#pragma unroll
  for (int mi = 0; mi < 4; mi++) {
#pragma unroll
    for (int ni = 0; ni < 4; ni++) {
      const int n = n0 + wn + ni * 16 + l15;
      const int s = n >> 10;           // 0=q 1=k
      const int h = (n >> 6) & 15;
      const int d = n & 63;
#pragma unroll
      for (int r = 0; r < 4; r++) {
        const int m = m0 + wm + mi * 16 + quad * 4 + r;
        const int b = m >> 11;         // /2048
        const int t = m & 2047;
        const int bh = (b << 4) + h;
        const float v = acc[mi][ni][r];
        if (s == 0) Qb[((size_t)bh * TT + t) * HD + d] = f2bf(v * QSCALE);
        else        Kb[((size_t)bh * TT + t) * HD + d] = f2bf(v);
      }
    }
  }
}

// ---------------- GEMM 2: out = AO @ w_out + b_out (fp32 out) ----------------
__global__ __launch_bounds__(256) void gemm_out(const unsigned short* __restrict__ A,
                                                const unsigned short* __restrict__ BT,
                                                const float* __restrict__ bias,
                                                float* __restrict__ out) {
  __shared__ unsigned short pool[16384];
  f32x4 acc[4][4] = {};
  const int m0 = blockIdx.y * 128, n0 = blockIdx.x * 128;
  gemm_core(A, BT, m0, n0, acc, pool, pool + 8192);
  const int tid = threadIdx.x, lane = tid & 63, wave = tid >> 6;
  const int quad = lane >> 4, l15 = lane & 15;
  const int wm = (wave & 1) * 64, wn = (wave >> 1) * 64;
#pragma unroll
  for (int mi = 0; mi < 4; mi++) {
#pragma unroll
    for (int ni = 0; ni < 4; ni++) {
      const int n = n0 + wn + ni * 16 + l15;
      const float bv = bias[n];
#pragma unroll
      for (int r = 0; r < 4; r++) {
        const int m = m0 + wm + mi * 16 + quad * 4 + r;
        out[(size_t)m * CE + n] = acc[mi][ni][r] + bv;
      }
    }
  }
}

// ---------------- causal flash attention: 32x32 T12 micro-kernel, 8-wave kv-split blocks -------
// Verified R11 micro-kernel (swapped QK^T, in-register P via cvt_pk+permlane32_swap, 0 bank
// conflicts) at R4's occupancy: 512 thr / 8 waves. Partner waves w and w+4 own the SAME 32
// q-rows; wave w takes kv sub-tile [kv0,kv0+32), wave w+4 takes [kv0+32,kv0+64) of each staged
// 64-kv tile (kt = w>>2, wave-uniform). Partial O/l are additive (fixed-reference softmax) and
// merged per phase through LDS scratch aliasing Ks/Vs. 16 waves/CU (vs R11's 8) hides the
// exp2/cvt chain. Balance (34 iters/block), staging, T1 swizzle, prefetch: R4-verbatim.
__global__ __launch_bounds__(512) void flash_attn(const unsigned short* __restrict__ Q,
                                                  const unsigned short* __restrict__ Kg,
                                                  const unsigned short* __restrict__ Vt,
                                                  unsigned short* __restrict__ AO) {
  __shared__ __align__(16) unsigned char smem[49152];  // Ks[64][72] | Vs[64][72]; merge aliases
  unsigned short (*Ks)[72] = (unsigned short (*)[72])smem;
  unsigned short (*Vs)[72] = (unsigned short (*)[72])(smem + 9216);
  float4* Sc = (float4*)smem;                          // merge scratch [4 grp][12 chunk][64 lane]
  const int flat = blockIdx.x + 8 * blockIdx.y;        // 0..511, hw dispatch order
  const int wu   = (flat & 7) * 64 + (flat >> 3);      // bijective remap
  const int qx   = wu & 7;                             // q-tile index 0..7
  const int bh   = wu >> 3;                            // head 0..63 (8 consecutive heads/XCD)
  const int tid = threadIdx.x, w = tid >> 6, lane = tid & 63;
  const int l31 = lane & 31, hi = lane >> 5;
  const int w2 = w & 3, hi2 = w >> 2;                  // row-group / kv-half
  const int b = bh >> 4, h = bh & 15;
  const unsigned short* Kbase = Kg + (size_t)bh * TT * HD;
  const unsigned short* Vbase = Vt + (size_t)bh * HD * TT;
  const int srow = tid >> 3;        // 0..63
  const int scol = (tid & 7) * 8;   // 0..56 ushorts (16B chunks)
  const bf16x8 ones = {1, 1, 1, 1, 1, 1, 1, 1};
  union V16 { f32x16 v; float4 c[4]; };

  for (int ph = 0; ph < 2; ph++) {
    const int pt = ph ? (15 - qx) : qx;
    const int q0 = pt * 128;
    const int n_it = 2 * pt + 2;
    const int wr = q0 + w2 * 32;      // this wave-pair's first Q row (32 rows)
    // Q fragments: B-operand of swapped QK^T. B[n=q=l31][k=ds*16+hi*8+j]
    bf16x8 qf[4];
#pragma unroll
    for (int ds_ = 0; ds_ < 4; ds_++)
      qf[ds_] = *(const bf16x8*)(Q + ((size_t)bh * TT + wr + l31) * HD + ds_ * 16 + hi * 8);
    f32x16 o0 = {}, o1 = {}, l_acc = {};
    // initial prefetch (tile 0 of this phase)
    uint4 kreg, vreg;
    kreg = *(const uint4*)(Kbase + (size_t)srow * HD + scol);
    vreg = *(const uint4*)(Vbase + (size_t)srow * TT + scol);
    for (int it = 0; it < n_it; it++) {
      const int kv0 = it * 64;
      // commit prefetched tile; issue next tile's loads BEFORE the barrier
      *(uint4*)&Ks[srow][scol] = kreg;
      *(uint4*)&Vs[srow][scol] = vreg;
      {
        const int itn = (it + 1 < n_it) ? it + 1 : it;
        const int kvn = itn * 64;
        kreg = *(const uint4*)(Kbase + (size_t)(kvn + srow) * HD + scol);
        vreg = *(const uint4*)(Vbase + (size_t)srow * TT + kvn + scol);
      }
      __syncthreads();
      const int kvs = kv0 + hi2 * 32;          // this wave's kv sub-tile start
      if (kvs <= wr + 31) {                    // wave-uniform causal skip
        // S^T = K Q^T over this 32-kv sub-tile: A[m=kv=l31][k], chained over 4 d-slices
        f32x16 sc = {};
        __builtin_amdgcn_s_setprio(1);
#pragma unroll
        for (int ds_ = 0; ds_ < 4; ds_++) {
          const bf16x8 kb = *(const bf16x8*)&Ks[hi2 * 32 + l31][ds_ * 16 + hi * 8];
          sc = __builtin_amdgcn_mfma_f32_32x32x16_bf16(kb, qf[ds_], sc, 0, 0, 0);
        }
        __builtin_amdgcn_s_setprio(0);
        // P = exp2(S), causal mask; value (reg r): kv = kvs+(r&3)+8*(r>>2)+4*hi, q = qg
        float p[16];
        const int qg = wr + l31;
        const int kvb = kvs + 4 * hi;
        if (kvs + 31 > wr) {
#pragma unroll
          for (int r = 0; r < 16; r++) {
            const int kvg = kvb + (r & 3) + 8 * (r >> 2);
            p[r] = exp2f(kvg <= qg ? sc[r] : -1e30f);
          }
        } else {
#pragma unroll
          for (int r = 0; r < 16; r++) p[r] = exp2f(sc[r]);
        }
        // T12: cvt_pk + permlane32_swap -> PV A-fragments (16-kv slices), zero LDS ops
        bf16x8 pa[2];
#pragma unroll
        for (int sl = 0; sl < 2; sl++) {
          unsigned a0 = cvtpk(p[8 * sl + 0], p[8 * sl + 1]);
          unsigned a1 = cvtpk(p[8 * sl + 2], p[8 * sl + 3]);
          unsigned a2 = cvtpk(p[8 * sl + 4], p[8 * sl + 5]);
          unsigned a3 = cvtpk(p[8 * sl + 6], p[8 * sl + 7]);
          asm volatile("v_permlane32_swap_b32 %0, %1" : "+v"(a0), "+v"(a2));
          asm volatile("v_permlane32_swap_b32 %0, %1" : "+v"(a1), "+v"(a3));
          union { unsigned u[4]; bf16x8 v; } c;
          c.u[0] = a0; c.u[1] = a1; c.u[2] = a2; c.u[3] = a3;
          pa[sl] = c.v;
        }
        // l += row-sum(P); O += P @ V  (B[n=d=l31(+32)][k=kv slice])
        __builtin_amdgcn_s_setprio(1);
        l_acc = __builtin_amdgcn_mfma_f32_32x32x16_bf16(pa[0], ones, l_acc, 0, 0, 0);
        l_acc = __builtin_amdgcn_mfma_f32_32x32x16_bf16(pa[1], ones, l_acc, 0, 0, 0);
#pragma unroll
        for (int sl = 0; sl < 2; sl++) {
          const bf16x8 vb0 = *(const bf16x8*)&Vs[l31][hi2 * 32 + sl * 16 + hi * 8];
          const bf16x8 vb1 = *(const bf16x8*)&Vs[32 + l31][hi2 * 32 + sl * 16 + hi * 8];
          o0 = __builtin_amdgcn_mfma_f32_32x32x16_bf16(pa[sl], vb0, o0, 0, 0, 0);
          o1 = __builtin_amdgcn_mfma_f32_32x32x16_bf16(pa[sl], vb1, o1, 0, 0, 0);
        }
        __builtin_amdgcn_s_setprio(0);
      }
      __syncthreads();  // LDS reads done before next iteration's commit
    }
    // ---- merge partner waves (hi2=1 -> hi2=0) via LDS scratch (aliases Ks/Vs) ----
    // Partner lanes hold identical (row, col) elements: same w2 -> same wr; same lane -> same
    // l31/hi -> same reg mapping. Scratch chunk c of group g at Sc[(g*12 + c)*64 + lane].
    if (hi2) {
      V16 a;
      a.v = o0;
#pragma unroll
      for (int c = 0; c < 4; c++) Sc[(w2 * 12 + c) * 64 + lane] = a.c[c];
      a.v = o1;
#pragma unroll
      for (int c = 0; c < 4; c++) Sc[(w2 * 12 + 4 + c) * 64 + lane] = a.c[c];
      a.v = l_acc;
#pragma unroll
      for (int c = 0; c < 4; c++) Sc[(w2 * 12 + 8 + c) * 64 + lane] = a.c[c];
    }
    __syncthreads();
    if (!hi2) {
      V16 a;
#pragma unroll
      for (int c = 0; c < 4; c++) a.c[c] = Sc[(w2 * 12 + c) * 64 + lane];
      o0 = o0 + a.v;
#pragma unroll
      for (int c = 0; c < 4; c++) a.c[c] = Sc[(w2 * 12 + 4 + c) * 64 + lane];
      o1 = o1 + a.v;
#pragma unroll
      for (int c = 0; c < 4; c++) a.c[c] = Sc[(w2 * 12 + 8 + c) * 64 + lane];
      l_acc = l_acc + a.v;
      // epilogue: O row q = wr+(r&3)+8*(r>>2)+4*hi, col d = dt*32+l31
      float rin[16];
#pragma unroll
      for (int r = 0; r < 16; r++) rin[r] = __builtin_amdgcn_rcpf(l_acc[r]);
#pragma unroll
      for (int r = 0; r < 16; r++) {
        const int row_g = wr + (r & 3) + 8 * (r >> 2) + 4 * hi;
        const size_t base = ((size_t)b * TT + row_g) * CE + h * 64;
        AO[base + l31]      = f2bf(o0[r] * rin[r]);
        AO[base + 32 + l31] = f2bf(o1[r] * rin[r]);
      }
    }
    __syncthreads();  // Sc reads done before next phase's Ks/Vs commit
  }
}

extern "C" void kernel_launch(void* const* d_in, const int* in_sizes, int n_in,
                              void* d_out, int out_size, void* d_ws, size_t ws_size,
                              hipStream_t stream) {
  const float* x     = (const float*)d_in[0];  // [4,2048,1024] f32
  const float* w_qkv = (const float*)d_in[1];  // [1024,3072] f32
  const float* w_out = (const float*)d_in[2];  // [1024,1024] f32
  const float* b_out = (const float*)d_in[3];  // [1024] f32
  float* out = (float*)d_out;                  // [4,2048,1024] f32

  unsigned short* ws  = (unsigned short*)d_ws;
  unsigned short* Xb  = ws;                                  // x bf16 [8192][1024]
  unsigned short* Wt1 = Xb  + (size_t)MM * CE;               // w_qkv^T  [3072][1024]
  unsigned short* Wt2 = Wt1 + (size_t)3072 * 1024;           // w_out^T  [1024][1024]
  unsigned short* Qb  = Wt2 + (size_t)1024 * 1024;           // [BH][T][64]
  unsigned short* Kb  = Qb  + (size_t)8388608;               // [BH][T][64]
  unsigned short* Vtb = Kb  + (size_t)8388608;               // [BH][64][T] (written by gemm_qkv)
  unsigned short* AO  = Vtb + (size_t)8388608;               // [M][1024] bf16

  prep      <<<dim3(12288), 256, 0, stream>>>(x, w_qkv, w_out, Xb, Wt1, Wt2);
  gemm_qkv  <<<dim3(24, 64), 256, 0, stream>>>(Xb, Wt1, Qb, Kb, Vtb);
  flash_attn<<<dim3(8, 64), 512, 0, stream>>>(Qb, Kb, Vtb, AO);
  gemm_out  <<<dim3(8, 64), 256, 0, stream>>>(AO, Wt2, b_out, out);
}